// Round 8
// baseline (597.622 us; speedup 1.0000x reference)
//
#include <hip/hip_runtime.h>
#include <hip/hip_bf16.h>
#include <hip/hip_cooperative_groups.h>
#include <cstdint>

namespace cg = cooperative_groups;

static constexpr int CAP      = 40;     // adj slots/node (80 B). P(deg>40)~3e-10.
static constexpr int BINSHIFT = 8;      // 256 nodes per bin
static constexpr int BINNODES = 1 << BINSHIFT;
static constexpr int BINCAP   = BINNODES * CAP / 2;  // 5120 pairs == adj seg bytes
static constexpr int EPB      = 1024;   // edges per bin task (4/thread)
static constexpr int OVMAX    = 1024;
static constexpr int NB2MAX   = 512;    // >= 2*nbins (392)
static constexpr int SMEM_SZ  = 21504;  // max(build 21504, bin 18688, fixup 8196)

typedef __attribute__((ext_vector_type(8))) short bf16x8;
typedef __attribute__((ext_vector_type(4))) float f32x4;

__device__ __forceinline__ float bf16lo(uint32_t u) { return __uint_as_float(u << 16); }
__device__ __forceinline__ float bf16hi(uint32_t u) { return __uint_as_float(u & 0xffff0000u); }
__device__ __forceinline__ unsigned short f2bf(float f) {
    __hip_bfloat16 h = __float2bfloat16(f);
    return *(unsigned short*)&h;
}

struct P {
    const int* src; const int* dst; int ne;
    uint32_t* pair; int* gcnt; int* ovcnt; int* ovlist;
    int nbins, nb2, gbin, gxc, ggo, n;
    const float* x; uint32_t* xb32; int nxw;
    const float* Wf; const float* Wb;
    unsigned short* WTf; unsigned short* WTb;
    int* cnt_f; int* cnt_b; float* dinv_f; float* dinv_b;
    const unsigned short* adj_f; const unsigned short* adj_b;
    const float* bfv; const float* bbv;
    float* out;
};

// ============================================================ PHASE A ======
// init: W -> bf16 transposed (8 tasks), zero gcnt+ovcnt (1 task, replaces
// the memset dispatch), x -> bf16 xb (gxc tasks). All streaming.
__device__ void phaseA(const P& A) {
    const int G = gridDim.x, tid = threadIdx.x;
    const int ta = 9 + A.gxc;
    for (int t = blockIdx.x; t < ta; t += G) {
        if (t < 8) {
            for (int idx = t * 2048 + tid; idx < (t + 1) * 2048; idx += 256) {
                int c = idx >> 7, k = idx & 127;
                A.WTf[c * 128 + k] = f2bf(A.Wf[k * 128 + c]);
                A.WTb[c * 128 + k] = f2bf(A.Wb[k * 128 + c]);
            }
        } else if (t == 8) {
            for (int i = tid; i < A.nb2 + 8; i += 256) A.gcnt[i] = 0;
        } else {
            int base = (t - 9) * 2048;
            int end = base + 2048; if (end > A.nxw) end = A.nxw;
            for (int i = base + tid; i < end; i += 256) {
                float2 v = ((const float2*)A.x)[i];
                A.xb32[i] = ((uint32_t)f2bf(v.y) << 16) | (uint32_t)f2bf(v.x);
            }
        }
    }
}

// ============================================================ PHASE B ======
// counting-sort pass 1: LDS histogram -> prefix -> one global atomic per
// (task,bin) reserve -> LDS-staged scatter (binof recorded) -> coalesced
// run writes.
__device__ void phaseB(const P& A, char* smem) {
    uint32_t*       stage = (uint32_t*)smem;               // 8192 B
    unsigned short* binof = (unsigned short*)(smem + 8192);// 4096 B
    int*            hist  = (int*)(smem + 12288);          // 2048 B
    int*            lofs  = (int*)(smem + 14336);          // 2048 B
    int*            gbase = (int*)(smem + 16384);          // 2048 B
    int*            chunk = (int*)(smem + 18432);          // 256 B
    const int G = gridDim.x, tid = threadIdx.x;
    const int nb2 = A.nb2;
    for (int t = blockIdx.x; t < A.gbin; t += G) {
        for (int i = tid; i < nb2; i += 256) hist[i] = 0;
        __syncthreads();
        int s[4], d[4];
        const int e0 = t * EPB + tid;
#pragma unroll
        for (int k = 0; k < 4; ++k) {
            int e = e0 + k * 256;
            bool v = e < A.ne;
            s[k] = v ? A.src[e] : -1;
            d[k] = v ? A.dst[e] : -1;
            if (v) {
                atomicAdd(&hist[d[k] >> BINSHIFT], 1);
                atomicAdd(&hist[A.nbins + (s[k] >> BINSHIFT)], 1);
            }
        }
        __syncthreads();
        const int nch = (nb2 + 7) >> 3;
        if (tid < nch) {
            int a = 0, base = tid << 3;
#pragma unroll
            for (int k = 0; k < 8; ++k) { int idx = base + k; if (idx < nb2) a += hist[idx]; }
            chunk[tid] = a;
        }
        __syncthreads();
        if (tid == 0) { int a = 0; for (int c = 0; c < nch; ++c) { int tt = chunk[c]; chunk[c] = a; a += tt; } }
        __syncthreads();
        for (int i = tid; i < nb2; i += 256) {
            int a = chunk[i >> 3];
            for (int k = (i >> 3) << 3; k < i; ++k) a += hist[k];
            lofs[i] = a;
        }
        __syncthreads();
        for (int i = tid; i < nb2; i += 256) {
            int c = hist[i];
            gbase[i] = c ? atomicAdd(&A.gcnt[i], c) : 0;
            hist[i] = lofs[i];
        }
        __syncthreads();
#pragma unroll
        for (int k = 0; k < 4; ++k) {
            if (s[k] >= 0) {
                int b0 = d[k] >> BINSHIFT;
                int p0 = atomicAdd(&hist[b0], 1);
                stage[p0] = ((uint32_t)d[k] << 16) | (uint32_t)s[k];
                binof[p0] = (unsigned short)b0;
                int b1 = A.nbins + (s[k] >> BINSHIFT);
                int p1 = atomicAdd(&hist[b1], 1);
                stage[p1] = ((uint32_t)s[k] << 16) | (uint32_t)d[k];
                binof[p1] = (unsigned short)b1;
            }
        }
        __syncthreads();
        int nval = A.ne - t * EPB; if (nval > EPB) nval = EPB; if (nval < 0) nval = 0;
        const int total = 2 * nval;
        for (int i = tid; i < total; i += 256) {
            int b = binof[i];
            int gidx = gbase[b] + (i - lofs[b]);
            if (gidx < BINCAP)
                A.pair[(size_t)b * BINCAP + gidx] = stage[i];
            else {
                int node = (int)(stage[i] >> 16);
                int q = atomicAdd(A.ovcnt, 1);
                if (q < OVMAX) A.ovlist[q] = (node << 1) | (b >= A.nbins ? 1 : 0);
            }
        }
        __syncthreads();
    }
}

// ============================================================ PHASE C ======
// counting-sort pass 2: coalesced pair read -> LDS-atomic rank -> 20 KB LDS
// bucket image -> coalesced in-place dump. cnt + dinv computed here.
__device__ void phaseC(const P& A, char* smem) {
    unsigned short* buck = (unsigned short*)smem;          // 20480 B
    int*            lcnt = (int*)(smem + 20480);           // 1024 B
    const int tid = threadIdx.x;
    for (int b = blockIdx.x; b < A.nb2; b += gridDim.x) {
        lcnt[tid] = 0;
        __syncthreads();
        int count = A.gcnt[b]; if (count > BINCAP) count = BINCAP;
        const uint32_t* pb = A.pair + (size_t)b * BINCAP;
        const int dir = b >= A.nbins ? 1 : 0;
        for (int i = tid; i < count; i += 256) {
            uint32_t p = pb[i];
            int l = (p >> 16) & (BINNODES - 1);
            int r = atomicAdd(&lcnt[l], 1);
            if (r < CAP) buck[l * CAP + r] = (unsigned short)(p & 0xffffu);
            else {
                int q = atomicAdd(A.ovcnt, 1);
                if (q < OVMAX)
                    A.ovlist[q] = (((((b - dir * A.nbins) << BINSHIFT) + l)) << 1) | dir;
            }
        }
        __syncthreads();
        const int node = ((b - dir * A.nbins) << BINSHIFT) + tid;
        if (node < A.n) {
            int c = lcnt[tid];
            if (dir) { A.cnt_b[node] = c; A.dinv_b[node] = rsqrtf(1.0f + (float)c); }
            else     { A.cnt_f[node] = c; A.dinv_f[node] = rsqrtf(1.0f + (float)c); }
        }
        uint32_t* seg = A.pair + (size_t)b * BINCAP;
        const uint32_t* b32 = (const uint32_t*)buck;
        for (int i = tid; i < BINCAP; i += 256) seg[i] = b32[i];
        __syncthreads();
    }
}

// ============================================================ PHASE D ======
// gather/agg: wave-per-node, grid-stride, barrier-free (r7 lesson: any
// block barrier after variable-length gather pays the straggler max).
// agg row (bf16, [f 64dw | b 64dw]) written to d_out; blocks 0-7 run the
// overflow fixup afterwards (no-op when ovcnt==0).
__device__ void accum_range(
        int j0, int j1, int ofs, float sc,
        const uint32_t* __restrict__ xb, int lane, float& a0, float& a1) {
    int j = j0;
    for (; j + 8 <= j1; j += 8) {
        int   o0 = __shfl(ofs, j + 0), o1 = __shfl(ofs, j + 1);
        int   o2 = __shfl(ofs, j + 2), o3 = __shfl(ofs, j + 3);
        int   o4 = __shfl(ofs, j + 4), o5 = __shfl(ofs, j + 5);
        int   o6 = __shfl(ofs, j + 6), o7 = __shfl(ofs, j + 7);
        float s0 = __shfl(sc, j + 0), s1 = __shfl(sc, j + 1);
        float s2 = __shfl(sc, j + 2), s3 = __shfl(sc, j + 3);
        float s4 = __shfl(sc, j + 4), s5 = __shfl(sc, j + 5);
        float s6 = __shfl(sc, j + 6), s7 = __shfl(sc, j + 7);
        uint32_t u0 = xb[(size_t)(o0 + lane)], u1 = xb[(size_t)(o1 + lane)];
        uint32_t u2 = xb[(size_t)(o2 + lane)], u3 = xb[(size_t)(o3 + lane)];
        uint32_t u4 = xb[(size_t)(o4 + lane)], u5 = xb[(size_t)(o5 + lane)];
        uint32_t u6 = xb[(size_t)(o6 + lane)], u7 = xb[(size_t)(o7 + lane)];
        a0 = fmaf(s0, bf16lo(u0), a0); a1 = fmaf(s0, bf16hi(u0), a1);
        a0 = fmaf(s1, bf16lo(u1), a0); a1 = fmaf(s1, bf16hi(u1), a1);
        a0 = fmaf(s2, bf16lo(u2), a0); a1 = fmaf(s2, bf16hi(u2), a1);
        a0 = fmaf(s3, bf16lo(u3), a0); a1 = fmaf(s3, bf16hi(u3), a1);
        a0 = fmaf(s4, bf16lo(u4), a0); a1 = fmaf(s4, bf16hi(u4), a1);
        a0 = fmaf(s5, bf16lo(u5), a0); a1 = fmaf(s5, bf16hi(u5), a1);
        a0 = fmaf(s6, bf16lo(u6), a0); a1 = fmaf(s6, bf16hi(u6), a1);
        a0 = fmaf(s7, bf16lo(u7), a0); a1 = fmaf(s7, bf16hi(u7), a1);
    }
    for (; j + 4 <= j1; j += 4) {
        int   o0 = __shfl(ofs, j + 0), o1 = __shfl(ofs, j + 1);
        int   o2 = __shfl(ofs, j + 2), o3 = __shfl(ofs, j + 3);
        float s0 = __shfl(sc, j + 0), s1 = __shfl(sc, j + 1);
        float s2 = __shfl(sc, j + 2), s3 = __shfl(sc, j + 3);
        uint32_t u0 = xb[(size_t)(o0 + lane)], u1 = xb[(size_t)(o1 + lane)];
        uint32_t u2 = xb[(size_t)(o2 + lane)], u3 = xb[(size_t)(o3 + lane)];
        a0 = fmaf(s0, bf16lo(u0), a0); a1 = fmaf(s0, bf16hi(u0), a1);
        a0 = fmaf(s1, bf16lo(u1), a0); a1 = fmaf(s1, bf16hi(u1), a1);
        a0 = fmaf(s2, bf16lo(u2), a0); a1 = fmaf(s2, bf16hi(u2), a1);
        a0 = fmaf(s3, bf16lo(u3), a0); a1 = fmaf(s3, bf16hi(u3), a1);
    }
    for (; j < j1; ++j) {
        int oj = __shfl(ofs, j); float sj = __shfl(sc, j);
        uint32_t uj = xb[(size_t)(oj + lane)];
        a0 = fmaf(sj, bf16lo(uj), a0); a1 = fmaf(sj, bf16hi(uj), a1);
    }
}

__device__ void phaseD(const P& A, char* smem) {
    const int tid = threadIdx.x;
    const int wv = tid >> 6, lane = tid & 63;
    const int NW = gridDim.x * 4;
    uint32_t* agg32 = (uint32_t*)A.out;

    for (int node = blockIdx.x * 4 + wv; node < A.n; node += NW) {
        int cf = A.cnt_f[node], cb = A.cnt_b[node];
        if (cf > CAP || cb > CAP) continue;        // fixup owns this row

        float dvsf = A.dinv_f[node], dvsb = A.dinv_b[node];
        uint32_t uv = A.xb32[(size_t)node * 64 + lane];
        float accf0 = dvsf * dvsf * bf16lo(uv), accf1 = dvsf * dvsf * bf16hi(uv);
        float accb0 = dvsb * dvsb * bf16lo(uv), accb1 = dvsb * dvsb * bf16hi(uv);

        const int mt = cf + cb;
        if (mt <= 64) {
            int ofs = 0; float sc = 0.f;
            if (lane < cf) {
                int nb = A.adj_f[node * CAP + lane];
                ofs = nb * 64;
                sc  = dvsf * A.dinv_f[nb];
            } else if (lane < mt) {
                int nb = A.adj_b[node * CAP + (lane - cf)];
                ofs = nb * 64;
                sc  = dvsb * A.dinv_b[nb];
            }
            accum_range(0,  cf, ofs, sc, A.xb32, lane, accf0, accf1);
            accum_range(cf, mt, ofs, sc, A.xb32, lane, accb0, accb1);
        } else {
            for (int j = 0; j < cf; ++j) {
                int nb = A.adj_f[node * CAP + j];
                float dj = dvsf * A.dinv_f[nb];
                uint32_t u = A.xb32[(size_t)nb * 64 + lane];
                accf0 = fmaf(dj, bf16lo(u), accf0); accf1 = fmaf(dj, bf16hi(u), accf1);
            }
            for (int j = 0; j < cb; ++j) {
                int nb = A.adj_b[node * CAP + j];
                float dj = dvsb * A.dinv_b[nb];
                uint32_t u = A.xb32[(size_t)nb * 64 + lane];
                accb0 = fmaf(dj, bf16lo(u), accb0); accb1 = fmaf(dj, bf16hi(u), accb1);
            }
        }
        agg32[(size_t)node * 128 + lane] =
            ((uint32_t)f2bf(accf1) << 16) | (uint32_t)f2bf(accf0);
        agg32[(size_t)node * 128 + 64 + lane] =
            ((uint32_t)f2bf(accb1) << 16) | (uint32_t)f2bf(accb0);
    }

    // ---- fixup (blocks 0..7): exact recompute of overflowed rows' agg ----
    if (blockIdx.x < 8) {
        __syncthreads();
        int nov = *A.ovcnt; if (nov > OVMAX) nov = OVMAX;
        if (nov == 0) return;
        int* lst = (int*)smem;                     // 8192 B
        int* lcp = (int*)(smem + 8192);
        for (int i = blockIdx.x; i < nov; i += 8) {
            int node = A.ovlist[i] >> 1;
            for (int d2 = 0; d2 < 2; ++d2) {
                const int* key = d2 ? A.src : A.dst;
                const int* val = d2 ? A.dst : A.src;
                const float* dinv = d2 ? A.dinv_b : A.dinv_f;
                float dvs = dinv[node];
                float s0 = 0.f, s1 = 0.f;
                if (tid < 64) {
                    uint32_t u = A.xb32[(size_t)node * 64 + tid];
                    s0 = dvs * bf16lo(u); s1 = dvs * bf16hi(u);
                }
                for (int start = 0; start < A.ne; start += 2048) {
                    if (tid == 0) *lcp = 0;
                    __syncthreads();
                    int end = min(start + 2048, A.ne);
                    for (int e2 = start + tid; e2 < end; e2 += 256)
                        if (key[e2] == node) { int q = atomicAdd(lcp, 1); lst[q] = val[e2]; }
                    __syncthreads();
                    int mm = *lcp;
                    if (tid < 64) {
                        for (int j = 0; j < mm; ++j) {
                            int nb = lst[j];
                            float dv = dinv[nb];
                            uint32_t u = A.xb32[(size_t)nb * 64 + tid];
                            s0 = fmaf(dv, bf16lo(u), s0);
                            s1 = fmaf(dv, bf16hi(u), s1);
                        }
                    }
                    __syncthreads();
                }
                if (tid < 64) {
                    float a0 = dvs * s0, a1 = dvs * s1;
                    agg32[(size_t)node * 128 + d2 * 64 + tid] =
                        ((uint32_t)f2bf(a1) << 16) | (uint32_t)f2bf(a0);
                }
                __syncthreads();
            }
        }
    }
}

// ============================================================ PHASE E ======
// out = relu(aggf @ Wf + aggb @ Wb + bias), in place over d_out (out row
// r's 512 B f32 == agg row r's 512 B bf16; each block touches only its own
// 32 rows; __syncthreads orders in-place reads before stores — r4-validated).
__device__ void phaseE(const P& A) {
    const int tid = threadIdx.x;
    const int wave = tid >> 6, lane = tid & 63;
    const int wm = wave >> 1, wh = wave & 1;
    const int q = lane >> 4, t16 = lane & 15;
    const unsigned short* agg = (const unsigned short*)A.out;
    for (int t = blockIdx.x; t < A.ggo; t += gridDim.x) {
        const int m0 = t * 32 + wm * 16;
        int arow = m0 + t16; if (arow >= A.n) arow = A.n - 1;
        const unsigned short* ra = agg + (size_t)arow * 256;
        bf16x8 af[4], ab[4];
#pragma unroll
        for (int s = 0; s < 4; ++s) {
            af[s] = *(const bf16x8*)(ra + s * 32 + q * 8);
            ab[s] = *(const bf16x8*)(ra + 128 + s * 32 + q * 8);
        }
        __syncthreads();     // all agg loads retired before in-place stores
#pragma unroll
        for (int t4 = 0; t4 < 4; ++t4) {
            const int col = wh * 64 + t4 * 16 + t16;
            const unsigned short* wrf = A.WTf + (size_t)col * 128;
            const unsigned short* wrb = A.WTb + (size_t)col * 128;
            f32x4 c = {0.f, 0.f, 0.f, 0.f};
#pragma unroll
            for (int s = 0; s < 4; ++s)
                c = __builtin_amdgcn_mfma_f32_16x16x32_bf16(
                        af[s], *(const bf16x8*)(wrf + s * 32 + q * 8), c, 0, 0, 0);
#pragma unroll
            for (int s = 0; s < 4; ++s)
                c = __builtin_amdgcn_mfma_f32_16x16x32_bf16(
                        ab[s], *(const bf16x8*)(wrb + s * 32 + q * 8), c, 0, 0, 0);
            const float bias = A.bfv[col] + A.bbv[col];
#pragma unroll
            for (int r = 0; r < 4; ++r) {
                int row = m0 + q * 4 + r;
                if (row < A.n)
                    A.out[(size_t)row * 128 + col] = fmaxf(c[r] + bias, 0.f);
            }
        }
    }
}

// ============================================================ MEGA =========
__global__ __launch_bounds__(256, 6) void k_mega(P A) {
    __shared__ __align__(16) char smem[SMEM_SZ];
    cg::grid_group g = cg::this_grid();
    phaseA(A);        g.sync();
    phaseB(A, smem);  g.sync();
    phaseC(A, smem);  g.sync();
    phaseD(A, smem);  g.sync();
    phaseE(A);
}

// fallback wrappers (used only if cooperative launch is unavailable)
__global__ __launch_bounds__(256) void k_pA(P A) { phaseA(A); }
__global__ __launch_bounds__(256) void k_pB(P A) {
    __shared__ __align__(16) char smem[SMEM_SZ]; phaseB(A, smem);
}
__global__ __launch_bounds__(256) void k_pC(P A) {
    __shared__ __align__(16) char smem[SMEM_SZ]; phaseC(A, smem);
}
__global__ __launch_bounds__(256) void k_pD(P A) {
    __shared__ __align__(16) char smem[SMEM_SZ]; phaseD(A, smem);
}
__global__ __launch_bounds__(256) void k_pE(P A) { phaseE(A); }

// ============================================================ launcher =====
extern "C" void kernel_launch(void* const* d_in, const int* in_sizes, int n_in,
                              void* d_out, int out_size, void* d_ws, size_t ws_size,
                              hipStream_t stream) {
    const float* x  = (const float*)d_in[0];
    const int*   ei = (const int*)d_in[1];
    const float* Wf = (const float*)d_in[2];
    const float* bf = (const float*)d_in[3];
    const float* Wb = (const float*)d_in[4];
    const float* bb = (const float*)d_in[5];

    const int n  = in_sizes[0] / 128;   // 50000
    const int ne = in_sizes[1] / 2;     // 625000
    const int nbins = (n + BINNODES - 1) >> BINSHIFT;   // 196
    const int nb2   = 2 * nbins;                        // 392

    // workspace (pair/adj overlay; agg lives in d_out rows)
    char* w = (char*)d_ws;
    uint32_t* pair = (uint32_t*)w;              w += (size_t)nb2 * BINCAP * 4;  // 8 MB
    uint32_t* xb32 = (uint32_t*)w;              w += (size_t)n * 64 * 4;        // 12.8 MB
    float* dinv_f = (float*)w;                  w += (size_t)n * 4;
    float* dinv_b = (float*)w;                  w += (size_t)n * 4;
    unsigned short* WTf = (unsigned short*)w;   w += 128 * 128 * 2;
    unsigned short* WTb = (unsigned short*)w;   w += 128 * 128 * 2;
    int* cnt_f = (int*)w;                       w += (size_t)n * 4;
    int* cnt_b = (int*)w;                       w += (size_t)n * 4;
    int* gcnt = (int*)w;                        w += (size_t)nb2 * 4;   // gcnt then
    int* ovcnt = (int*)w;                       w += 8 * 4;             // ovcnt: zeroed
    int* ovlist = (int*)w;                      w += OVMAX * 4;         // by phase A

    P a;
    a.src = ei; a.dst = ei + ne; a.ne = ne;
    a.pair = pair; a.gcnt = gcnt; a.ovcnt = ovcnt; a.ovlist = ovlist;
    a.nbins = nbins; a.nb2 = nb2;
    a.gbin = (ne + EPB - 1) / EPB;              // 611
    a.gxc  = (n * 64 + 2047) / 2048;            // 1563
    a.ggo  = (n + 31) / 32;                     // 1563
    a.n = n;
    a.x = x; a.xb32 = xb32; a.nxw = n * 64;
    a.Wf = Wf; a.Wb = Wb; a.WTf = WTf; a.WTb = WTb;
    a.cnt_f = cnt_f; a.cnt_b = cnt_b; a.dinv_f = dinv_f; a.dinv_b = dinv_b;
    a.adj_f = (const unsigned short*)pair;
    a.adj_b = (const unsigned short*)pair + (size_t)nbins * BINNODES * CAP;
    a.bfv = bf; a.bbv = bb;
    a.out = (float*)d_out;

    // cooperative single-dispatch path; grid = co-resident capacity
    int nbmax = 0;
    hipError_t err = hipOccupancyMaxActiveBlocksPerMultiprocessor(&nbmax, k_mega, 256, 0);
    bool launched = false;
    if (err == hipSuccess && nbmax > 0) {
        int grid = nbmax * 256;                  // 256 CUs on MI355X
        void* ka[] = { (void*)&a };
        err = hipLaunchCooperativeKernel(k_mega, dim3(grid), dim3(256), ka, 0, stream);
        launched = (err == hipSuccess);
    }
    if (!launched) {
        // fallback: same phases as separate dispatches (≈ r6 behavior)
        k_pA<<<9 + a.gxc, 256, 0, stream>>>(a);
        k_pB<<<a.gbin,    256, 0, stream>>>(a);
        k_pC<<<a.nb2,     256, 0, stream>>>(a);
        k_pD<<<(n + 3)/4, 256, 0, stream>>>(a);
        k_pE<<<a.ggo,     256, 0, stream>>>(a);
    }
}

// Round 9
// 177.373 us; speedup vs baseline: 3.3693x; 3.3693x over previous
//
#include <hip/hip_runtime.h>
#include <hip/hip_bf16.h>
#include <cstdint>

static constexpr int BLK      = 256;
static constexpr int CAP      = 40;     // adj slots/node (80 B). P(deg>40)~3e-10.
static constexpr int BINSHIFT = 8;      // 256 nodes per bin
static constexpr int BINNODES = 1 << BINSHIFT;
static constexpr int BINCAP   = BINNODES * CAP / 2;  // 5120 pairs == adj seg bytes
static constexpr int EPB      = 2048;   // edges per binning block (8/thread; r9: 2x
                                        // amortizes per-bin prefix+reserve phases)
static constexpr int OVMAX    = 1024;
static constexpr int NB2MAX   = 512;    // >= 2*nbins (392)

typedef __attribute__((ext_vector_type(8))) short bf16x8;
typedef __attribute__((ext_vector_type(4))) float f32x4;

__device__ __forceinline__ float bf16lo(uint32_t u) { return __uint_as_float(u << 16); }
__device__ __forceinline__ float bf16hi(uint32_t u) { return __uint_as_float(u & 0xffff0000u); }
__device__ __forceinline__ float bf16f(unsigned short u) { return __uint_as_float((uint32_t)u << 16); }
__device__ __forceinline__ unsigned short f2bf(float f) {
    __hip_bfloat16 h = __float2bfloat16(f);
    return *(unsigned short*)&h;
}

// ============================================================ BIN + CONV ===
// blocks [0, gbin):      counting-sort pass 1 (LDS-staged coalesced appends;
//   binof[] recorded at scatter time). EPB=2048: per-bin phases amortize
//   over 2x pairs; write runs ~21 pairs (84 B) -> fewer sub-line stores;
//   reserve atomics halve to ~120K.
// blocks [gbin,+gxc):    x -> bf16 (xb), streaming (hides bin latency).
// blocks [..,+8):        W -> bf16 transposed.
__global__ __launch_bounds__(BLK) void k_bin_conv(
        const int* __restrict__ src, const int* __restrict__ dst, int ne,
        uint32_t* __restrict__ pair, int* __restrict__ gcnt,
        int* __restrict__ ovcnt, int* __restrict__ ovlist, int nbins, int gbin,
        const float* __restrict__ x, uint32_t* __restrict__ xb32, int nxw, int gxc,
        const float* __restrict__ Wf, const float* __restrict__ Wb,
        unsigned short* __restrict__ WTf, unsigned short* __restrict__ WTb) {
    const int bid = blockIdx.x, tid = threadIdx.x;
    if (bid < gbin) {
        __shared__ uint32_t stage[EPB * 2];              // 16 KB
        __shared__ unsigned short binof[EPB * 2];        // 8 KB
        __shared__ int hist[NB2MAX];                     // histogram, then cursor
        __shared__ int lofs[NB2MAX];                     // local exclusive prefix
        __shared__ int gbase[NB2MAX];                    // reserved global base
        __shared__ int chunk[NB2MAX / 8];
        const int nb2 = 2 * nbins;
        for (int i = tid; i < nb2; i += BLK) hist[i] = 0;
        __syncthreads();

        int s[8], d[8];
        const int e0 = bid * EPB + tid;
#pragma unroll
        for (int k = 0; k < 8; ++k) {
            int e = e0 + k * BLK;
            bool v = e < ne;
            s[k] = v ? src[e] : -1;
            d[k] = v ? dst[e] : -1;
            if (v) {
                atomicAdd(&hist[d[k] >> BINSHIFT], 1);
                atomicAdd(&hist[nbins + (s[k] >> BINSHIFT)], 1);
            }
        }
        __syncthreads();

        const int nch = (nb2 + 7) >> 3;
        if (tid < nch) {
            int a = 0, base = tid << 3;
#pragma unroll
            for (int k = 0; k < 8; ++k) { int idx = base + k; if (idx < nb2) a += hist[idx]; }
            chunk[tid] = a;
        }
        __syncthreads();
        if (tid == 0) { int a = 0; for (int c = 0; c < nch; ++c) { int t = chunk[c]; chunk[c] = a; a += t; } }
        __syncthreads();
        for (int i = tid; i < nb2; i += BLK) {           // strided (r3 lesson)
            int a = chunk[i >> 3];
            for (int k = (i >> 3) << 3; k < i; ++k) a += hist[k];
            lofs[i] = a;
        }
        __syncthreads();
        for (int i = tid; i < nb2; i += BLK) {
            int c = hist[i];
            gbase[i] = c ? atomicAdd(&gcnt[i], c) : 0;
            hist[i] = lofs[i];
        }
        __syncthreads();
#pragma unroll
        for (int k = 0; k < 8; ++k) {
            if (s[k] >= 0) {
                int b0 = d[k] >> BINSHIFT;
                int p0 = atomicAdd(&hist[b0], 1);
                stage[p0] = ((uint32_t)d[k] << 16) | (uint32_t)s[k];
                binof[p0] = (unsigned short)b0;
                int b1 = nbins + (s[k] >> BINSHIFT);
                int p1 = atomicAdd(&hist[b1], 1);
                stage[p1] = ((uint32_t)s[k] << 16) | (uint32_t)d[k];
                binof[p1] = (unsigned short)b1;
            }
        }
        __syncthreads();
        int nval = ne - bid * EPB; if (nval > EPB) nval = EPB; if (nval < 0) nval = 0;
        const int total = 2 * nval;
        for (int i = tid; i < total; i += BLK) {
            int b = binof[i];
            int gidx = gbase[b] + (i - lofs[b]);
            if (gidx < BINCAP)
                pair[(size_t)b * BINCAP + gidx] = stage[i];
            else {
                int node = (int)(stage[i] >> 16);
                int q = atomicAdd(ovcnt, 1);
                if (q < OVMAX) ovlist[q] = (node << 1) | (b >= nbins ? 1 : 0);
            }
        }
        return;
    }
    if (bid < gbin + gxc) {
        int base = (bid - gbin) * 2048;
        int end = base + 2048; if (end > nxw) end = nxw;
        for (int i = base + tid; i < end; i += BLK) {
            float2 v = ((const float2*)x)[i];
            xb32[i] = ((uint32_t)f2bf(v.y) << 16) | (uint32_t)f2bf(v.x);
        }
        return;
    }
    int wb = bid - gbin - gxc;                           // 0..7
    for (int idx = wb * 2048 + tid; idx < (wb + 1) * 2048; idx += BLK) {
        int c = idx >> 7, k = idx & 127;
        WTf[c * 128 + k] = f2bf(Wf[k * 128 + c]);
        WTb[c * 128 + k] = f2bf(Wb[k * 128 + c]);
    }
}

// ============================================================ BUILD ========
// counting-sort pass 2: coalesced pair read -> LDS-atomic rank -> 20 KB LDS
// bucket image -> coalesced in-place dump. cnt + dinv computed here.
__global__ __launch_bounds__(BLK) void k_build(
        uint32_t* __restrict__ pair, const int* __restrict__ gcnt,
        int* __restrict__ cnt_f, int* __restrict__ cnt_b,
        float* __restrict__ dinv_f, float* __restrict__ dinv_b,
        int* __restrict__ ovcnt, int* __restrict__ ovlist,
        int n, int nbins) {
    const int bid = blockIdx.x, tid = threadIdx.x;
    __shared__ unsigned short buck[BINNODES * CAP];      // 20 KB
    __shared__ int lcnt[BINNODES];
    lcnt[tid] = 0;                                       // BLK == BINNODES
    __syncthreads();
    int count = gcnt[bid]; if (count > BINCAP) count = BINCAP;
    const uint32_t* pb = pair + (size_t)bid * BINCAP;
    const int dir = bid >= nbins ? 1 : 0;
    for (int i = tid; i < count; i += BLK) {
        uint32_t p = pb[i];
        int l = (p >> 16) & (BINNODES - 1);
        int r = atomicAdd(&lcnt[l], 1);
        if (r < CAP) buck[l * CAP + r] = (unsigned short)(p & 0xffffu);
        else {
            int q = atomicAdd(ovcnt, 1);
            if (q < OVMAX)
                ovlist[q] = (((((bid - dir * nbins) << BINSHIFT) + l)) << 1) | dir;
        }
    }
    __syncthreads();
    const int node = ((bid - dir * nbins) << BINSHIFT) + tid;
    if (node < n) {
        int c = lcnt[tid];
        if (dir) { cnt_b[node] = c; dinv_b[node] = rsqrtf(1.0f + (float)c); }
        else     { cnt_f[node] = c; dinv_f[node] = rsqrtf(1.0f + (float)c); }
    }
    uint32_t* seg = pair + (size_t)bid * BINCAP;
    const uint32_t* b32 = (const uint32_t*)buck;
    for (int i = tid; i < BINCAP; i += BLK) seg[i] = b32[i];
}

// ============================================================ GATHER+GEMM ==
// r9: barrier-FREE fusion. r5's fused kernel paid ~23us at the block
// barrier (all 4 waves wait on the slowest gather chain). Now: each wave
// gathers its 4 nodes, fences LDS, atomicAdd(&done); the LAST wave (sees
// done==3) runs the whole 16x256x128 MFMA epilogue alone; the other 3
// retire immediately — their SIMD slots go to other blocks' gather waves.
// Epilogue math identical to r5 (validated). Straggler max is gone.
__device__ __forceinline__ void accum_range(
        int j0, int j1, int ofs, float sc,
        const uint32_t* __restrict__ xb, int lane, float& a0, float& a1) {
    int j = j0;
    for (; j + 8 <= j1; j += 8) {
        int   o0 = __shfl(ofs, j + 0), o1 = __shfl(ofs, j + 1);
        int   o2 = __shfl(ofs, j + 2), o3 = __shfl(ofs, j + 3);
        int   o4 = __shfl(ofs, j + 4), o5 = __shfl(ofs, j + 5);
        int   o6 = __shfl(ofs, j + 6), o7 = __shfl(ofs, j + 7);
        float s0 = __shfl(sc, j + 0), s1 = __shfl(sc, j + 1);
        float s2 = __shfl(sc, j + 2), s3 = __shfl(sc, j + 3);
        float s4 = __shfl(sc, j + 4), s5 = __shfl(sc, j + 5);
        float s6 = __shfl(sc, j + 6), s7 = __shfl(sc, j + 7);
        uint32_t u0 = xb[(size_t)(o0 + lane)], u1 = xb[(size_t)(o1 + lane)];
        uint32_t u2 = xb[(size_t)(o2 + lane)], u3 = xb[(size_t)(o3 + lane)];
        uint32_t u4 = xb[(size_t)(o4 + lane)], u5 = xb[(size_t)(o5 + lane)];
        uint32_t u6 = xb[(size_t)(o6 + lane)], u7 = xb[(size_t)(o7 + lane)];
        a0 = fmaf(s0, bf16lo(u0), a0); a1 = fmaf(s0, bf16hi(u0), a1);
        a0 = fmaf(s1, bf16lo(u1), a0); a1 = fmaf(s1, bf16hi(u1), a1);
        a0 = fmaf(s2, bf16lo(u2), a0); a1 = fmaf(s2, bf16hi(u2), a1);
        a0 = fmaf(s3, bf16lo(u3), a0); a1 = fmaf(s3, bf16hi(u3), a1);
        a0 = fmaf(s4, bf16lo(u4), a0); a1 = fmaf(s4, bf16hi(u4), a1);
        a0 = fmaf(s5, bf16lo(u5), a0); a1 = fmaf(s5, bf16hi(u5), a1);
        a0 = fmaf(s6, bf16lo(u6), a0); a1 = fmaf(s6, bf16hi(u6), a1);
        a0 = fmaf(s7, bf16lo(u7), a0); a1 = fmaf(s7, bf16hi(u7), a1);
    }
    for (; j + 4 <= j1; j += 4) {
        int   o0 = __shfl(ofs, j + 0), o1 = __shfl(ofs, j + 1);
        int   o2 = __shfl(ofs, j + 2), o3 = __shfl(ofs, j + 3);
        float s0 = __shfl(sc, j + 0), s1 = __shfl(sc, j + 1);
        float s2 = __shfl(sc, j + 2), s3 = __shfl(sc, j + 3);
        uint32_t u0 = xb[(size_t)(o0 + lane)], u1 = xb[(size_t)(o1 + lane)];
        uint32_t u2 = xb[(size_t)(o2 + lane)], u3 = xb[(size_t)(o3 + lane)];
        a0 = fmaf(s0, bf16lo(u0), a0); a1 = fmaf(s0, bf16hi(u0), a1);
        a0 = fmaf(s1, bf16lo(u1), a0); a1 = fmaf(s1, bf16hi(u1), a1);
        a0 = fmaf(s2, bf16lo(u2), a0); a1 = fmaf(s2, bf16hi(u2), a1);
        a0 = fmaf(s3, bf16lo(u3), a0); a1 = fmaf(s3, bf16hi(u3), a1);
    }
    for (; j < j1; ++j) {
        int oj = __shfl(ofs, j); float sj = __shfl(sc, j);
        uint32_t uj = xb[(size_t)(oj + lane)];
        a0 = fmaf(sj, bf16lo(uj), a0); a1 = fmaf(sj, bf16hi(uj), a1);
    }
}

__global__ __launch_bounds__(BLK, 8) void k_gather_gemm(
        const int* __restrict__ cnt_f, const int* __restrict__ cnt_b,
        const unsigned short* __restrict__ adj_f,
        const unsigned short* __restrict__ adj_b,
        const float* __restrict__ dinv_f, const float* __restrict__ dinv_b,
        const uint32_t* __restrict__ xb32,
        const unsigned short* __restrict__ WTf,
        const unsigned short* __restrict__ WTb,
        const float* __restrict__ bfv, const float* __restrict__ bbv,
        float* __restrict__ out, int n, int gnode2,
        const int* __restrict__ ovcnt, const int* __restrict__ ovlist,
        const int* __restrict__ src, const int* __restrict__ dst, int ne) {
    __shared__ __align__(16) char smemU[16 * 528];  // aggL rows | fixup lst
    __shared__ int ovflag[16];
    __shared__ int donec;
    __shared__ int lc;
    const int bid = blockIdx.x, tid = threadIdx.x;
    if (bid < gnode2) {
        uint32_t* aggL = (uint32_t*)smemU;          // row pitch 132 dwords
        const int wave = tid >> 6, lane = tid & 63;
        const int node0 = bid * 16;
        if (tid == 0) donec = 0;
        __syncthreads();                             // init only; pre-divergence

        for (int i4 = 0; i4 < 4; ++i4) {
            const int row = wave * 4 + i4;
            const int node = node0 + row;
            int cf = 0, cb = 0;
            bool skip = node >= n;
            if (!skip) { cf = cnt_f[node]; cb = cnt_b[node]; skip = (cf > CAP || cb > CAP); }
            if (lane == 0) ovflag[row] = skip ? 1 : 0;
            if (skip) continue;

            float dvsf = dinv_f[node], dvsb = dinv_b[node];
            uint32_t uv = xb32[(size_t)node * 64 + lane];
            float accf0 = dvsf * dvsf * bf16lo(uv), accf1 = dvsf * dvsf * bf16hi(uv);
            float accb0 = dvsb * dvsb * bf16lo(uv), accb1 = dvsb * dvsb * bf16hi(uv);

            const int mt = cf + cb;
            if (mt <= 64) {
                int ofs = 0; float sc = 0.f;
                if (lane < cf) {
                    int nb = adj_f[node * CAP + lane];
                    ofs = nb * 64;
                    sc  = dvsf * dinv_f[nb];
                } else if (lane < mt) {
                    int nb = adj_b[node * CAP + (lane - cf)];
                    ofs = nb * 64;
                    sc  = dvsb * dinv_b[nb];
                }
                accum_range(0,  cf, ofs, sc, xb32, lane, accf0, accf1);
                accum_range(cf, mt, ofs, sc, xb32, lane, accb0, accb1);
            } else {
                for (int j = 0; j < cf; ++j) {
                    int nb = adj_f[node * CAP + j];
                    float dj = dvsf * dinv_f[nb];
                    uint32_t u = xb32[(size_t)nb * 64 + lane];
                    accf0 = fmaf(dj, bf16lo(u), accf0); accf1 = fmaf(dj, bf16hi(u), accf1);
                }
                for (int j = 0; j < cb; ++j) {
                    int nb = adj_b[node * CAP + j];
                    float dj = dvsb * dinv_b[nb];
                    uint32_t u = xb32[(size_t)nb * 64 + lane];
                    accb0 = fmaf(dj, bf16lo(u), accb0); accb1 = fmaf(dj, bf16hi(u), accb1);
                }
            }
            aggL[row * 132 + lane] =
                ((uint32_t)f2bf(accf1) << 16) | (uint32_t)f2bf(accf0);
            aggL[row * 132 + 64 + lane] =
                ((uint32_t)f2bf(accb1) << 16) | (uint32_t)f2bf(accb0);
        }

        // ---- last-wave epilogue handoff (no block barrier) ----
        __threadfence_block();                       // LDS writes visible
        int prev = 0;
        if (lane == 0) prev = atomicAdd(&donec, 1);
        prev = __shfl(prev, 0);
        if (prev != 3) return;                       // 3 waves retire now
        __threadfence_block();

        // ---- epilogue: this wave computes all 16 rows x 128 cols ----
        const int q = lane >> 4, t16 = lane & 15;
        const char* arow = smemU + t16 * 528;
        bf16x8 a[8];
#pragma unroll
        for (int s = 0; s < 8; ++s)
            a[s] = *(const bf16x8*)(arow + s * 64 + q * 16);
#pragma unroll
        for (int t = 0; t < 8; ++t) {
            const int col = t * 16 + t16;
            const unsigned short* wrf = WTf + (size_t)col * 128;
            const unsigned short* wrb = WTb + (size_t)col * 128;
            f32x4 c = {0.f, 0.f, 0.f, 0.f};
#pragma unroll
            for (int s = 0; s < 4; ++s)
                c = __builtin_amdgcn_mfma_f32_16x16x32_bf16(
                        a[s], *(const bf16x8*)(wrf + s * 32 + q * 8), c, 0, 0, 0);
#pragma unroll
            for (int s = 0; s < 4; ++s)
                c = __builtin_amdgcn_mfma_f32_16x16x32_bf16(
                        a[4 + s], *(const bf16x8*)(wrb + s * 32 + q * 8), c, 0, 0, 0);
            const float bias = bfv[col] + bbv[col];
#pragma unroll
            for (int r = 0; r < 4; ++r) {
                int row = q * 4 + r;
                int node2 = node0 + row;
                if (node2 < n && !ovflag[row])
                    out[(size_t)node2 * 128 + col] = fmaxf(c[r] + bias, 0.f);
            }
        }
        return;
    }

    // ---- fixup blocks: exact recompute of overflowed rows (agg + GEMV) ----
    int nov = *ovcnt; if (nov > OVMAX) nov = OVMAX;
    if (nov == 0) return;
    int* lst = (int*)smemU;                           // 2048 ints <= 8448 B
    float* aggfl = (float*)(smemU);                   // reused after lst phase
    __shared__ float afix[256];                       // [f 128 | b 128]
    for (int i = bid - gnode2; i < nov; i += 8) {
        int node = ovlist[i] >> 1;
        for (int d2 = 0; d2 < 2; ++d2) {
            const int* key = d2 ? src : dst;
            const int* val = d2 ? dst : src;
            const float* dinv = d2 ? dinv_b : dinv_f;
            float dvs = dinv[node];
            float s0 = 0.f, s1 = 0.f;
            if (tid < 64) {
                uint32_t u = xb32[(size_t)node * 64 + tid];
                s0 = dvs * bf16lo(u); s1 = dvs * bf16hi(u);
            }
            for (int start = 0; start < ne; start += 2048) {
                if (tid == 0) lc = 0;
                __syncthreads();
                int end = min(start + 2048, ne);
                for (int e2 = start + tid; e2 < end; e2 += BLK)
                    if (key[e2] == node) { int qq = atomicAdd(&lc, 1); lst[qq] = val[e2]; }
                __syncthreads();
                int mm = lc;
                if (tid < 64) {
                    for (int j = 0; j < mm; ++j) {
                        int nb = lst[j];
                        float dv = dinv[nb];
                        uint32_t u = xb32[(size_t)nb * 64 + tid];
                        s0 = fmaf(dv, bf16lo(u), s0);
                        s1 = fmaf(dv, bf16hi(u), s1);
                    }
                }
                __syncthreads();
            }
            if (tid < 64) {                 // bf16-round to match main path
                afix[d2 * 128 + 2 * tid]     = bf16f(f2bf(dvs * s0));
                afix[d2 * 128 + 2 * tid + 1] = bf16f(f2bf(dvs * s1));
            }
            __syncthreads();
        }
        if (tid < 128) {
            const int col = tid;
            float acc = bfv[col] + bbv[col];
            const unsigned short* wrf = WTf + (size_t)col * 128;
            const unsigned short* wrb = WTb + (size_t)col * 128;
            for (int k = 0; k < 128; ++k) {
                acc = fmaf(afix[k],       bf16f(wrf[k]), acc);
                acc = fmaf(afix[128 + k], bf16f(wrb[k]), acc);
            }
            out[(size_t)node * 128 + col] = fmaxf(acc, 0.f);
        }
        __syncthreads();
        (void)aggfl;
    }
}

// ============================================================ launcher =====
extern "C" void kernel_launch(void* const* d_in, const int* in_sizes, int n_in,
                              void* d_out, int out_size, void* d_ws, size_t ws_size,
                              hipStream_t stream) {
    const float* x  = (const float*)d_in[0];
    const int*   ei = (const int*)d_in[1];
    const float* Wf = (const float*)d_in[2];
    const float* bf = (const float*)d_in[3];
    const float* Wb = (const float*)d_in[4];
    const float* bb = (const float*)d_in[5];

    const int n  = in_sizes[0] / 128;   // 50000
    const int ne = in_sizes[1] / 2;     // 625000
    const int* src = ei;
    const int* dst = ei + ne;
    float* out = (float*)d_out;

    const int nbins = (n + BINNODES - 1) >> BINSHIFT;   // 196
    const int nb2   = 2 * nbins;                        // 392

    // workspace (pair/adj overlay; agg lives only in LDS)
    char* w = (char*)d_ws;
    uint32_t* pair = (uint32_t*)w;              w += (size_t)nb2 * BINCAP * 4;  // 8 MB
    uint32_t* xb32 = (uint32_t*)w;              w += (size_t)n * 64 * 4;        // 12.8 MB
    float* dinv_f = (float*)w;                  w += (size_t)n * 4;
    float* dinv_b = (float*)w;                  w += (size_t)n * 4;
    unsigned short* WTf = (unsigned short*)w;   w += 128 * 128 * 2;
    unsigned short* WTb = (unsigned short*)w;   w += 128 * 128 * 2;
    int* cnt_f = (int*)w;                       w += (size_t)n * 4;
    int* cnt_b = (int*)w;                       w += (size_t)n * 4;
    int* gcnt = (int*)w;                        w += (size_t)nb2 * 4;   // -- zero
    int* ovcnt = (int*)w;                       w += 8 * 4;             //  region
    int* ovlist = (int*)w;                      w += OVMAX * 4;

    const unsigned short* adj_f = (const unsigned short*)pair;
    const unsigned short* adj_b = adj_f + (size_t)nbins * BINNODES * CAP;

    const int gbin   = (ne + EPB - 1) / EPB;            // 306
    const int gxc    = (n * 64 + 2047) / 2048;          // 1563
    const int gnode2 = (n + 15) / 16;                   // 3125

    hipMemsetAsync(gcnt, 0, (size_t)(nb2 + 8) * 4, stream);

    k_bin_conv<<<gbin + gxc + 8, BLK, 0, stream>>>(src, dst, ne,
                                                   pair, gcnt, ovcnt, ovlist,
                                                   nbins, gbin,
                                                   x, xb32, n * 64, gxc,
                                                   Wf, Wb, WTf, WTb);

    k_build<<<nb2, BLK, 0, stream>>>(pair, gcnt, cnt_f, cnt_b,
                                     dinv_f, dinv_b, ovcnt, ovlist, n, nbins);

    k_gather_gemm<<<gnode2 + 8, BLK, 0, stream>>>(cnt_f, cnt_b, adj_f, adj_b,
                                                  dinv_f, dinv_b, xb32,
                                                  WTf, WTb, bf, bb,
                                                  out, n, gnode2,
                                                  ovcnt, ovlist, src, dst, ne);
}